// Round 2
// baseline (396.726 us; speedup 1.0000x reference)
//
#include <hip/hip_runtime.h>

#define NN 262144
#define RANK 16
#define NNZ_K 1310720

struct P8 { const float* p[8]; };

// ---------------------------------------------------------------------------
// K1: t_{l,h}[r] = sum_{j in half h} v_l[j][r] * z[j]
// Each block handles a 512-element chunk (always inside one half per level,
// since min half size = 1024 and chunks are 512-aligned).
// Lane layout: 4 threads per element (each covers a float4 of rank dims).
// ---------------------------------------------------------------------------
__global__ __launch_bounds__(256) void k_levels_t(P8 v, const float* __restrict__ z,
                                                  float* __restrict__ tg) {
    __shared__ float zl[512];
    __shared__ float red[8][4][16];
    const int tid  = threadIdx.x;
    const int base = blockIdx.x * 512;

    zl[tid]       = z[base + tid];
    zl[tid + 256] = z[base + tid + 256];
    __syncthreads();

    const int q = tid & 3;      // rank quad
    const int e = tid >> 2;     // element-in-group 0..63

    float4 acc[8];
#pragma unroll
    for (int l = 0; l < 8; ++l) acc[l] = make_float4(0.f, 0.f, 0.f, 0.f);

#pragma unroll
    for (int it = 0; it < 8; ++it) {
        const int jloc = it * 64 + e;
        const size_t j = (size_t)(base + jloc);
        const float zz = zl[jloc];
#pragma unroll
        for (int l = 0; l < 8; ++l) {
            const float4 vv = *(const float4*)(v.p[l] + j * RANK + q * 4);
            acc[l].x += vv.x * zz;
            acc[l].y += vv.y * zz;
            acc[l].z += vv.z * zz;
            acc[l].w += vv.w * zz;
        }
    }

    const int lane = tid & 63;
    const int wv   = tid >> 6;
#pragma unroll
    for (int l = 0; l < 8; ++l) {
        float4 a = acc[l];
#pragma unroll
        for (int m = 4; m <= 32; m <<= 1) {     // reduce over lanes with same (lane&3)
            a.x += __shfl_xor(a.x, m);
            a.y += __shfl_xor(a.y, m);
            a.z += __shfl_xor(a.z, m);
            a.w += __shfl_xor(a.w, m);
        }
        if (lane < 4) *(float4*)&red[l][wv][lane * 4] = a;
    }
    __syncthreads();

    if (tid < 128) {
        const int l = tid >> 4;
        const int r = tid & 15;
        const float s = red[l][0][r] + red[l][1][r] + red[l][2][r] + red[l][3][r];
        const int h = base >> (17 - l);                    // half index at level l
        atomicAdd(&tg[(((2 << l) - 2) + h) * 16 + r], s);
    }
}

// ---------------------------------------------------------------------------
// K2: w[i] = [L (L^T x)]_i + 1e-4*x[i] + sum_l u_l[i][:] . t_{l, sibling_half}
// 256 threads handle 8 leaf blocks (256 rows). Leaf blocks staged in LDS with
// row stride 33 (conflict-free for both column and row passes).
// ---------------------------------------------------------------------------
__global__ __launch_bounds__(256) void k_apply(const float* __restrict__ leaf, P8 u,
                                               const float* __restrict__ z,
                                               const float* __restrict__ tg,
                                               float* __restrict__ w) {
    __shared__ float Lp[8 * 1056];   // 8 blocks of 32x33
    __shared__ float xl[256];
    __shared__ float t32[8][32];
    __shared__ float tl[8][16];

    const int tid  = threadIdx.x;
    const int base = blockIdx.x * 256;

    // stage leaf blocks: 2048 float4s, coalesced global, padded LDS
    const float4* Lg = (const float4*)(leaf + (size_t)base * 32);
#pragma unroll
    for (int k = 0; k < 8; ++k) {
        const int fi = tid + k * 256;          // 0..2047
        const float4 val = Lg[fi];
        const int lb  = fi >> 8;
        const int off = (fi & 255) * 4;
        const int row = off >> 5;
        const int col = off & 31;
        float* d = &Lp[lb * 1056 + row * 33 + col];
        d[0] = val.x; d[1] = val.y; d[2] = val.z; d[3] = val.w;
    }
    xl[tid] = z[base + tid];
    if (tid < 128) {
        const int l = tid >> 4;
        const int r = tid & 15;
        const int h = base >> (17 - l);
        tl[l][r] = tg[(((2 << l) - 2) + (h ^ 1)) * 16 + r];   // sibling half
    }
    __syncthreads();

    // t32[lb][c] = sum_row L[row][c] * x[row]
    {
        const int lb = tid >> 5;
        const int c  = tid & 31;
        const float* Lb = &Lp[lb * 1056];
        const float* xb = &xl[lb * 32];
        float s = 0.f;
#pragma unroll
        for (int row = 0; row < 32; ++row)
            s += Lb[row * 33 + c] * xb[row];
        t32[lb][c] = s;
    }
    __syncthreads();

    {
        const int lb = tid >> 5;
        const int r  = tid & 31;
        const float* Lb = &Lp[lb * 1056 + r * 33];
        float acc = 1e-4f * xl[tid];
#pragma unroll
        for (int c = 0; c < 32; ++c)
            acc += Lb[c] * t32[lb][c];

        const size_t i = (size_t)(base + tid);
#pragma unroll
        for (int l = 0; l < 8; ++l) {
            const float4* up = (const float4*)(u.p[l] + i * RANK);
            const float4 a0 = up[0], a1 = up[1], a2 = up[2], a3 = up[3];
            acc += a0.x * tl[l][0]  + a0.y * tl[l][1]  + a0.z * tl[l][2]  + a0.w * tl[l][3]
                 + a1.x * tl[l][4]  + a1.y * tl[l][5]  + a1.z * tl[l][6]  + a1.w * tl[l][7]
                 + a2.x * tl[l][8]  + a2.y * tl[l][9]  + a2.z * tl[l][10] + a2.w * tl[l][11]
                 + a3.x * tl[l][12] + a3.y * tl[l][13] + a3.z * tl[l][14] + a3.w * tl[l][15];
        }
        w[i] = acc;
    }
}

// ---------------------------------------------------------------------------
// K3: y[rows[k]] += vals[k] * w[cols[k]]   (indices are int32 on device —
// the harness converts all integer inputs to int32)
// ---------------------------------------------------------------------------
__global__ __launch_bounds__(256) void k_spmv(const int* __restrict__ idx,
                                              const float* __restrict__ vals,
                                              const float* __restrict__ w,
                                              float* __restrict__ y) {
    const int k = blockIdx.x * 256 + threadIdx.x;
    const int row = idx[k];
    const int col = idx[NNZ_K + k];
    atomicAdd(&y[row], vals[k] * w[col]);
}

// ---------------------------------------------------------------------------
// K4: sum((y - z)^2)  -> loss accumulator (zeroed by memset)
// ---------------------------------------------------------------------------
__global__ __launch_bounds__(256) void k_loss(const float* __restrict__ y,
                                              const float* __restrict__ z,
                                              float* __restrict__ loss) {
    const int i = blockIdx.x * 256 + threadIdx.x;
    const float d = y[i] - z[i];
    float s = d * d;
#pragma unroll
    for (int m = 32; m >= 1; m >>= 1) s += __shfl_down(s, m);
    __shared__ float r4[4];
    const int lane = threadIdx.x & 63, wv = threadIdx.x >> 6;
    if (lane == 0) r4[wv] = s;
    __syncthreads();
    if (threadIdx.x == 0) atomicAdd(loss, r4[0] + r4[1] + r4[2] + r4[3]);
}

__global__ void k_fin(const float* __restrict__ loss, float* __restrict__ out) {
    out[0] = loss[0] * (1.0f / (float)NN);
}

// ---------------------------------------------------------------------------
extern "C" void kernel_launch(void* const* d_in, const int* in_sizes, int n_in,
                              void* d_out, int out_size, void* d_ws, size_t ws_size,
                              hipStream_t stream) {
    const float* leaf = (const float*)d_in[0];
    P8 u, v;
    for (int l = 0; l < 8; ++l) {
        u.p[l] = (const float*)d_in[1 + 2 * l];
        v.p[l] = (const float*)d_in[2 + 2 * l];
    }
    const int*   Aidx  = (const int*)d_in[17];
    const float* Avals = (const float*)d_in[18];
    const float* z     = (const float*)d_in[19];

    float* ws   = (float*)d_ws;
    float* tg   = ws;                 // 8160 used (8192 reserved)
    float* loss = ws + 8192;          // 1 float
    float* y    = ws + 16384;         // N floats
    float* w    = ws + 16384 + NN;    // N floats

    // zero t-table, loss slot, y
    hipMemsetAsync(d_ws, 0, (size_t)(16384 + NN) * sizeof(float), stream);

    k_levels_t<<<NN / 512, 256, 0, stream>>>(v, z, tg);
    k_apply  <<<NN / 256, 256, 0, stream>>>(leaf, u, z, tg, w);
    k_spmv   <<<NNZ_K / 256, 256, 0, stream>>>(Aidx, Avals, w, y);
    k_loss   <<<NN / 256, 256, 0, stream>>>(y, z, loss);
    k_fin    <<<1, 1, 0, stream>>>(loss, (float*)d_out);
}